// Round 16
// baseline (148.976 us; speedup 1.0000x reference)
//
#include <hip/hip_runtime.h>
#include <hip/hip_bf16.h>
#include <cstdint>

// ---------------- CSR build ----------------
// NOTE: harness passes integer inputs as int32.
// cnt is memset to 0; node i's segment length = cnt[i]+1 (self-loop at slot off[i]).
// LESSON (R10): do NOT fuse returning atomics ahead of a __syncthreads in the SAME
// block — barrier's vmcnt(0) drain serializes them. Different-block merging is safe.

// bf16 pack with round-to-nearest-even
__device__ inline unsigned short f2bf(float f) {
  unsigned u = __float_as_uint(f);
  unsigned r = (u + 0x7FFFu + ((u >> 16) & 1u)) >> 16;
  return (unsigned short)r;
}

typedef __attribute__((ext_vector_type(8))) short bf16x8;
typedef __attribute__((ext_vector_type(4))) float f32x4;

// MERGED: weight-prep blocks [0, nwb) (W1^T bf16 + W2^T f32) + count blocks [nwb, ...).
__global__ __launch_bounds__(256) void k_prep(const float* __restrict__ W,
                                              unsigned short* __restrict__ wT,
                                              const float* __restrict__ W2,
                                              float* __restrict__ W2T,
                                              const int* __restrict__ ei,
                                              int* __restrict__ cnt,
                                              int* __restrict__ rank,
                                              int E, int nwb) {
  if ((int)blockIdx.x < nwb) {
    int idx = blockIdx.x * 256 + threadIdx.x;
    const int base = 128 * 136;
    if (idx < base) {
      int c = idx / 136, k = idx % 136;  // wT[c][k] = W[k][c]
      wT[idx] = (k < 128) ? f2bf(W[k * 128 + c]) : (unsigned short)0;
    } else if (idx < base + 1280) {
      int j = idx - base;
      int c = j >> 7, k = j & 127;       // W2T[c][k] = W2[k][c]
      W2T[c * 128 + k] = W2[k * 10 + c];
    }
  } else {
    // 4 edges per thread: int4 dst read, 4 atomics in flight, int4 rank write.
    int i4 = (blockIdx.x - nwb) * 256 + threadIdx.x;
    int e0 = i4 * 4;
    if (e0 + 3 < E) {
      int4 d = *(const int4*)&ei[E + e0];
      int4 r;
      r.x = atomicAdd(&cnt[d.x], 1);
      r.y = atomicAdd(&cnt[d.y], 1);
      r.z = atomicAdd(&cnt[d.z], 1);
      r.w = atomicAdd(&cnt[d.w], 1);
      *(int4*)&rank[e0] = r;
    } else if (e0 < E) {
      for (int e = e0; e < E; ++e) rank[e] = atomicAdd(&cnt[ei[E + e]], 1);
    }
  }
}

// SINGLE-KERNEL exclusive scan of (cnt[i]+1): each block recomputes its global
// prefix by summing all preceding elements (redundant but parallel: ~4.8MB L2),
// then local 1024-scan. Replaces bsum+scanb+scanc (3 launches -> 1).
__global__ __launch_bounds__(1024) void k_scan(const int* __restrict__ cnt,
                                               int* __restrict__ off, int n, int nb) {
  __shared__ int wsum[16];
  __shared__ int bpre_s;
  int b = blockIdx.x, t = threadIdx.x;
  int lane = t & 63, wd = t >> 6;
  int lim = b << 10;
  // phase 1: block prefix = sum of (cnt[i]+1) for i < lim
  int pre = 0;
  for (int i = t; i < lim; i += 1024) pre += cnt[i] + 1;
#pragma unroll
  for (int d = 1; d < 64; d <<= 1) pre += __shfl_xor(pre, d);
  if (lane == 0) wsum[wd] = pre;
  __syncthreads();
  if (t == 0) {
    int s = 0;
#pragma unroll
    for (int j = 0; j < 16; ++j) s += wsum[j];
    bpre_s = s;
  }
  __syncthreads();     // t0 done reading wsum + bpre_s visible
  int bpre = bpre_s;
  // phase 2: local exclusive scan of this block's 1024 elements
  int i = lim + t;
  int v = (i < n) ? cnt[i] + 1 : 0;
  int orig = v;
#pragma unroll
  for (int d = 1; d < 64; d <<= 1) {
    int u = __shfl_up(v, d, 64);
    if (lane >= d) v += u;
  }
  if (lane == 63) wsum[wd] = v;
  __syncthreads();
  if (wd == 0) {
    int s = (lane < 16) ? wsum[lane] : 0;
#pragma unroll
    for (int d = 1; d < 16; d <<= 1) {
      int u = __shfl_up(s, d, 64);
      if (lane >= d) s += u;
    }
    if (lane < 16) wsum[lane] = s;
  }
  __syncthreads();
  int vv = v;
  if (wd > 0) vv += wsum[wd - 1];
  if (i < n) off[i] = bpre + vv - orig;
  if (b == nb - 1 && t == 1023) off[n] = bpre + vv;  // grand total (= E + n)
}

// MERGED: gemm1 blocks [0, g1) + scatter blocks [g1, ...).
__global__ __launch_bounds__(256) void k_gs(const float* __restrict__ x,
                                            const unsigned short* __restrict__ wTg,
                                            const float* __restrict__ a_src,
                                            const float* __restrict__ a_dst,
                                            unsigned short* __restrict__ h1,
                                            float* __restrict__ as1,
                                            float* __restrict__ ad1, int n,
                                            const int* __restrict__ ei,
                                            const int* __restrict__ off,
                                            const int* __restrict__ rank,
                                            int* __restrict__ adj, int E, int g1) {
  __shared__ __align__(16) unsigned short xs[64][136];   // 17.4 KB
  __shared__ __align__(16) unsigned short wt[128][136];  // 34.8 KB
  if ((int)blockIdx.x >= g1) {
    // ---- scatter: atomic-free, 4 edges per thread; self-loops in tail range ----
    int idx = (blockIdx.x - g1) * 256 + threadIdx.x;
    int nq = (E + 3) >> 2;
    if (idx < nq) {
      int e0 = idx * 4;
      if (e0 + 3 < E) {
        int4 s = *(const int4*)&ei[e0];
        int4 d = *(const int4*)&ei[E + e0];
        int4 r = *(const int4*)&rank[e0];
        adj[off[d.x] + 1 + r.x] = s.x;
        adj[off[d.y] + 1 + r.y] = s.y;
        adj[off[d.z] + 1 + r.z] = s.z;
        adj[off[d.w] + 1 + r.w] = s.w;
      } else {
        for (int e = e0; e < E; ++e) adj[off[ei[E + e]] + 1 + rank[e]] = ei[e];
      }
    } else if (idx < nq + n) {
      int i = idx - nq;
      adj[off[i]] = i;  // self loop
    }
    return;
  }
  // ---- gemm1 via MFMA bf16 (R9-proven): h1(bf16) = x @ W1, fused alphas ----
  int t = threadIdx.x;
  int lane = t & 63, w = t >> 6;
  int l15 = lane & 15;
  {
    const uint4* src = (const uint4*)wTg;
    uint4* dst = (uint4*)&wt[0][0];
    for (int i = t; i < 2176; i += 256) dst[i] = src[i];
  }
  float as_c[8], ad_c[8];
#pragma unroll
  for (int ct = 0; ct < 8; ++ct) {
    as_c[ct] = a_src[ct * 16 + l15];
    ad_c[ct] = a_dst[ct * 16 + l15];
  }
  int tr = t >> 5, tc = t & 31;
  int arow = w * 16 + l15;          // A-frag row within tile
  int koff = (lane >> 4) * 8;       // K offset within 32-wide block
  int row0 = blockIdx.x << 6;
#pragma unroll
  for (int rr = 0; rr < 64; rr += 8) {
    int r = rr + tr, gr = row0 + r;
    float4 v = make_float4(0.f, 0.f, 0.f, 0.f);
    if (gr < n) v = *(const float4*)&x[(size_t)gr * 128 + tc * 4];
    ushort4 b;
    b.x = f2bf(v.x); b.y = f2bf(v.y); b.z = f2bf(v.z); b.w = f2bf(v.w);
    *(ushort4*)&xs[r][tc * 4] = b;
  }
  __syncthreads();
  f32x4 acc[8];
#pragma unroll
  for (int ct = 0; ct < 8; ++ct) acc[ct] = f32x4{0.f, 0.f, 0.f, 0.f};
#pragma unroll
  for (int kb = 0; kb < 4; ++kb) {
    bf16x8 a = *(bf16x8*)&xs[arow][kb * 32 + koff];
#pragma unroll
    for (int ct = 0; ct < 8; ++ct) {
      bf16x8 b = *(bf16x8*)&wt[ct * 16 + l15][kb * 32 + koff];
      acc[ct] = __builtin_amdgcn_mfma_f32_16x16x32_bf16(a, b, acc[ct], 0, 0, 0);
    }
  }
  // epilogue: h1 (bf16) + per-head alpha projections
  int orow = (lane >> 4) * 4;
#pragma unroll
  for (int r = 0; r < 4; ++r) {
    int gr = row0 + w * 16 + orow + r;
    bool ok = gr < n;
#pragma unroll
    for (int ct = 0; ct < 8; ++ct)
      if (ok) h1[(size_t)gr * 128 + ct * 16 + l15] = f2bf(acc[ct][r]);
#pragma unroll
    for (int h = 0; h < 4; ++h) {
      float ps = acc[2 * h][r] * as_c[2 * h] + acc[2 * h + 1][r] * as_c[2 * h + 1];
      float pd = acc[2 * h][r] * ad_c[2 * h] + acc[2 * h + 1][r] * ad_c[2 * h + 1];
      ps += __shfl_xor(ps, 1); ps += __shfl_xor(ps, 2);
      ps += __shfl_xor(ps, 4); ps += __shfl_xor(ps, 8);
      pd += __shfl_xor(pd, 1); pd += __shfl_xor(pd, 2);
      pd += __shfl_xor(pd, 4); pd += __shfl_xor(pd, 8);
      if (ok && l15 == 0) {
        as1[gr * 4 + h] = ps;
        ad1[gr * 4 + h] = pd;
      }
    }
  }
}

// ---------------- conv1 + FUSED gemm2 (W2T vectorized): single-pass aggregation,
// then the 16-lane group computes h2 = x2 @ W2 in-register via W2T float4 reads.
// x2 never materializes. as2 packed into h2 row slot 10 (one 64B line in conv2).

__global__ __launch_bounds__(256) void k_conv1(const int* __restrict__ off,
                                               const int* __restrict__ adj,
                                               const unsigned short* __restrict__ h1,
                                               const float* __restrict__ as1,
                                               const float* __restrict__ ad1,
                                               const float* __restrict__ b1,
                                               const float* __restrict__ W2T,
                                               const float* __restrict__ a_src2,
                                               const float* __restrict__ a_dst2,
                                               float* __restrict__ h2,
                                               float* __restrict__ ad2, int n) {
  int wid = (blockIdx.x * 256 + threadIdx.x) >> 6;  // global wave id
  int lane = threadIdx.x & 63;
  int grp = lane >> 4;       // node slot within wave
  int l16 = lane & 15;
  int node = wid * 4 + grp;
  bool active = node < n;
  int beg = 0, end = 0;
  float4 adv = make_float4(0.f, 0.f, 0.f, 0.f);
  if (active) {
    beg = off[node];
    end = off[node + 1];
    adv = *(const float4*)&ad1[node * 4];
  }
  int hh = (l16 >> 2) & 3;   // head for this lane's channels AND its weight slot
  int esub = l16 & 3;        // edge slot within chunk quarter
  float adh = hh == 0 ? adv.x : hh == 1 ? adv.y : hh == 2 ? adv.z : adv.w;
  int c0 = l16 * 8;          // 8 bf16 channels per lane
  float acc[8] = {};
  float zacc = 0.f;
  for (int e0 = beg; e0 < end; e0 += 16) {
    int sa = 0, sb = 0, sc = 0, sd = 0;
    float wa = 0.f, wb = 0.f, wc = 0.f, wdd = 0.f;
    int ea = e0 + esub, eb = e0 + 4 + esub, ec = e0 + 8 + esub, ed = e0 + 12 + esub;
    if (ea < end) {
      sa = adj[ea];
      float v = as1[sa * 4 + hh] + adh;
      v = v > 0.f ? v : 0.2f * v;
      wa = __expf(v);
    }
    if (eb < end) {
      sb = adj[eb];
      float v = as1[sb * 4 + hh] + adh;
      v = v > 0.f ? v : 0.2f * v;
      wb = __expf(v);
    }
    if (ec < end) {
      sc = adj[ec];
      float v = as1[sc * 4 + hh] + adh;
      v = v > 0.f ? v : 0.2f * v;
      wc = __expf(v);
    }
    if (ed < end) {
      sd = adj[ed];
      float v = as1[sd * 4 + hh] + adh;
      v = v > 0.f ? v : 0.2f * v;
      wdd = __expf(v);
    }
    zacc += wa + wb + wc + wdd;
    // consume 16 edges; src/weight broadcast from lane (lane&60)|(j&3)
#pragma unroll
    for (int j = 0; j < 16; ++j) {
      int sl = (lane & 60) | (j & 3);
      int s = (j < 4) ? __shfl(sa, sl) : (j < 8) ? __shfl(sb, sl)
             : (j < 12) ? __shfl(sc, sl) : __shfl(sd, sl);
      float w = (j < 4) ? __shfl(wa, sl) : (j < 8) ? __shfl(wb, sl)
             : (j < 12) ? __shfl(wc, sl) : __shfl(wdd, sl);
      if (e0 + j < end) {  // uniform within the 16-lane group
        uint4 q = *(const uint4*)&h1[(size_t)s * 128 + c0];
        acc[0] += w * __uint_as_float(q.x << 16);
        acc[1] += w * __uint_as_float(q.x & 0xffff0000u);
        acc[2] += w * __uint_as_float(q.y << 16);
        acc[3] += w * __uint_as_float(q.y & 0xffff0000u);
        acc[4] += w * __uint_as_float(q.z << 16);
        acc[5] += w * __uint_as_float(q.z & 0xffff0000u);
        acc[6] += w * __uint_as_float(q.w << 16);
        acc[7] += w * __uint_as_float(q.w & 0xffff0000u);
      }
    }
  }
  // z for head hh: reduce over the 4 esub lanes (lane bits 0,1)
  zacc += __shfl_xor(zacc, 1);
  zacc += __shfl_xor(zacc, 2);
  // bias + ELU -> o[8] = this lane's 8 channels of x2[node]
  float inv = 1.0f / (zacc + 1e-16f);
  float o[8];
#pragma unroll
  for (int j = 0; j < 8; ++j) {
    float v = acc[j] * inv + b1[c0 + j];
    o[j] = v > 0.f ? v : __expf(v) - 1.f;  // ELU fused
  }
  // ---- fused gemm2 via W2T: 2 float4 loads per output channel ----
  float acc2[10];
#pragma unroll
  for (int c = 0; c < 10; ++c) {
    float4 a = *(const float4*)&W2T[c * 128 + c0];
    float4 b = *(const float4*)&W2T[c * 128 + c0 + 4];
    acc2[c] = o[0] * a.x + o[1] * a.y + o[2] * a.z + o[3] * a.w +
              o[4] * b.x + o[5] * b.y + o[6] * b.z + o[7] * b.w;
  }
#pragma unroll
  for (int c = 0; c < 10; ++c) {
#pragma unroll
    for (int d = 1; d < 16; d <<= 1) acc2[c] += __shfl_xor(acc2[c], d);
  }
  if (active && l16 == 0) {
    float s = 0.f, ds = 0.f;
#pragma unroll
    for (int c = 0; c < 10; ++c) {
      h2[(size_t)node * 16 + c] = acc2[c];   // padded stride 16
      s += acc2[c] * a_src2[c];
      ds += acc2[c] * a_dst2[c];
    }
    h2[(size_t)node * 16 + 10] = s;          // as2 packed into the same 64B line
    ad2[node] = ds;
  }
}

// ---------------- conv2: SINGLE-PASS; ONE 64B line per edge (h2 row + packed as2) ----

__global__ __launch_bounds__(256) void k_conv2(const int* __restrict__ off,
                                               const int* __restrict__ adj,
                                               const float* __restrict__ h2,
                                               const float* __restrict__ ad2,
                                               const float* __restrict__ b2,
                                               float* __restrict__ out, int n) {
  int wid = (blockIdx.x * 256 + threadIdx.x) >> 6;
  int lane = threadIdx.x & 63;
  int grp = lane >> 4;
  int l16 = lane & 15;
  int node = wid * 4 + grp;
  bool active = node < n;
  int beg = 0, end = 0;
  float adv = 0.f;
  if (active) {
    beg = off[node];
    end = off[node + 1];
    adv = ad2[node];
  }
  float z = 0.f;
  float acc[10] = {};
  for (int e = beg + l16; e < end; e += 16) {
    int s = adj[e];
    const float4* hp = (const float4*)&h2[(size_t)s * 16];
    float4 hA = hp[0], hB = hp[1], hC = hp[2];   // hC = {h8, h9, as2, pad}
    float v = hC.z + adv;
    v = v > 0.f ? v : 0.2f * v;
    float wgt = __expf(v);
    z += wgt;
    acc[0] += wgt * hA.x; acc[1] += wgt * hA.y;
    acc[2] += wgt * hA.z; acc[3] += wgt * hA.w;
    acc[4] += wgt * hB.x; acc[5] += wgt * hB.y;
    acc[6] += wgt * hB.z; acc[7] += wgt * hB.w;
    acc[8] += wgt * hC.x; acc[9] += wgt * hC.y;
  }
#pragma unroll
  for (int c = 0; c < 10; ++c) {
#pragma unroll
    for (int d = 1; d < 16; d <<= 1) acc[c] += __shfl_xor(acc[c], d);
  }
#pragma unroll
  for (int d = 1; d < 16; d <<= 1) z += __shfl_xor(z, d);
  if (active && l16 == 0) {
    float inv = 1.0f / (z + 1e-16f);
#pragma unroll
    for (int c = 0; c < 10; ++c) out[(size_t)node * 10 + c] = acc[c] * inv + b2[c];
  }
}

// ---------------- launch ----------------

extern "C" void kernel_launch(void* const* d_in, const int* in_sizes, int n_in,
                              void* d_out, int out_size, void* d_ws, size_t ws_size,
                              hipStream_t stream) {
  const float* x      = (const float*)d_in[0];
  const int* ei       = (const int*)d_in[1];
  const float* W1     = (const float*)d_in[2];
  const float* a_src1 = (const float*)d_in[3];
  const float* a_dst1 = (const float*)d_in[4];
  const float* b1     = (const float*)d_in[5];
  const float* W2     = (const float*)d_in[6];
  const float* a_src2 = (const float*)d_in[7];
  const float* a_dst2 = (const float*)d_in[8];
  const float* b2     = (const float*)d_in[9];
  float* out = (float*)d_out;
  const int N = in_sizes[0] / 128;
  const int E = in_sizes[1] / 2;

  char* ws = (char*)d_ws;
  size_t o = 0;
  auto alloc = [&](size_t bytes) -> void* {
    void* p = ws + o;
    o += (bytes + 255) & ~(size_t)255;
    return p;
  };
  int* cnt    = (int*)alloc((size_t)N * 4);
  int* rank_  = (int*)alloc((size_t)E * 4);
  int* offs   = (int*)alloc((size_t)(N + 1) * 4);
  int* adj    = (int*)alloc((size_t)(E + N) * 4);
  unsigned short* h1  = (unsigned short*)alloc((size_t)N * 128 * 2);  // bf16
  unsigned short* wTg = (unsigned short*)alloc(128 * 136 * 2);        // bf16 W1^T padded
  float* W2T  = (float*)alloc(10 * 128 * 4);                          // f32 W2^T
  float* a_s1 = (float*)alloc((size_t)N * 4 * 4);
  float* a_d1 = (float*)alloc((size_t)N * 4 * 4);
  float* h2   = (float*)alloc((size_t)N * 16 * 4);   // padded stride 16; slot10 = as2
  float* a_d2 = (float*)alloc((size_t)N * 4);

  int nb = (N + 1023) / 1024;
  int g1 = (N + 63) / 64;                              // gemm1 tiles
  int nq = (E + 3) / 4;
  int nwb = (128 * 136 + 1280 + 255) / 256;            // weight-prep blocks
  int ncb = (nq + 255) / 256;                          // count blocks
  int nsb = (nq + N + 255) / 256;                      // scatter blocks
  hipMemsetAsync(cnt, 0, (size_t)N * 4, stream);
  k_prep<<<nwb + ncb, 256, 0, stream>>>(W1, wTg, W2, W2T, ei, cnt, rank_, E, nwb);
  k_scan<<<nb, 1024, 0, stream>>>(cnt, offs, N, nb);
  k_gs<<<g1 + nsb, 256, 0, stream>>>(x, wTg, a_src1, a_dst1, h1, a_s1, a_d1, N,
                                     ei, offs, rank_, adj, E, g1);
  k_conv1<<<(N + 15) / 16, 256, 0, stream>>>(offs, adj, h1, a_s1, a_d1, b1,
                                             W2T, a_src2, a_dst2, h2, a_d2, N);
  k_conv2<<<(N + 15) / 16, 256, 0, stream>>>(offs, adj, h2, a_d2, b2, out, N);
}

// Round 17
// 144.000 us; speedup vs baseline: 1.0346x; 1.0346x over previous
//
#include <hip/hip_runtime.h>
#include <hip/hip_bf16.h>
#include <cstdint>

// ---------------- CSR build ----------------
// NOTE: harness passes integer inputs as int32.
// cnt is memset to 0; node i's segment length = cnt[i]+1 (self-loop at slot off[i]).
// LESSON (R10): do NOT fuse returning atomics ahead of a __syncthreads in the SAME
// block — barrier's vmcnt(0) drain serializes them. Different-block merging is safe.
// LESSON (R16): hoisted float4 weight loads in conv1's epilogue cost a wave slot
// (VGPR 36->44, occupancy 52->37%) — scalar W2 reads are FASTER here. Reverted.

// bf16 pack with round-to-nearest-even
__device__ inline unsigned short f2bf(float f) {
  unsigned u = __float_as_uint(f);
  unsigned r = (u + 0x7FFFu + ((u >> 16) & 1u)) >> 16;
  return (unsigned short)r;
}

typedef __attribute__((ext_vector_type(8))) short bf16x8;
typedef __attribute__((ext_vector_type(4))) float f32x4;

// MERGED: wprep blocks [0, nwb) + count blocks [nwb, ...). Independent work.
__global__ __launch_bounds__(256) void k_prep(const float* __restrict__ W,
                                              unsigned short* __restrict__ wT,
                                              const int* __restrict__ ei,
                                              int* __restrict__ cnt,
                                              int* __restrict__ rank,
                                              int E, int nwb) {
  if ((int)blockIdx.x < nwb) {
    // W1 -> bf16 transposed, padded rows of 136
    int idx = blockIdx.x * 256 + threadIdx.x;
    if (idx < 128 * 136) {
      int c = idx / 136, k = idx % 136;  // wT[c][k] = W[k][c]
      wT[idx] = (k < 128) ? f2bf(W[k * 128 + c]) : (unsigned short)0;
    }
  } else {
    // 4 edges per thread: int4 dst read, 4 atomics in flight, int4 rank write.
    int i4 = (blockIdx.x - nwb) * 256 + threadIdx.x;
    int e0 = i4 * 4;
    if (e0 + 3 < E) {
      int4 d = *(const int4*)&ei[E + e0];
      int4 r;
      r.x = atomicAdd(&cnt[d.x], 1);
      r.y = atomicAdd(&cnt[d.y], 1);
      r.z = atomicAdd(&cnt[d.z], 1);
      r.w = atomicAdd(&cnt[d.w], 1);
      *(int4*)&rank[e0] = r;
    } else if (e0 < E) {
      for (int e = e0; e < E; ++e) rank[e] = atomicAdd(&cnt[ei[E + e]], 1);
    }
  }
}

__global__ __launch_bounds__(1024) void k_bsum(const int* __restrict__ cnt,
                                               int* __restrict__ bsum, int n) {
  __shared__ int ws_[16];
  int i = blockIdx.x * 1024 + threadIdx.x;
  int v = (i < n) ? cnt[i] + 1 : 0;   // +1: self-loop
#pragma unroll
  for (int d = 1; d < 64; d <<= 1) v += __shfl_xor(v, d);
  int lane = threadIdx.x & 63, wid = threadIdx.x >> 6;
  if (lane == 0) ws_[wid] = v;
  __syncthreads();
  if (threadIdx.x == 0) {
    int s = 0;
#pragma unroll
    for (int j = 0; j < 16; ++j) s += ws_[j];
    bsum[blockIdx.x] = s;
  }
}

// single-wave exclusive scan of block sums (nb <= 64 for N=50000)
__global__ __launch_bounds__(64) void k_scanb(int* bsum, int* off, int nb, int n) {
  int t = threadIdx.x;
  int v = (t < nb) ? bsum[t] : 0;
  int orig = v;
#pragma unroll
  for (int d = 1; d < 64; d <<= 1) {
    int u = __shfl_up(v, d, 64);
    if (t >= d) v += u;
  }
  if (t < nb) bsum[t] = v - orig;   // exclusive block offset
  if (t == 63) off[n] = v;          // grand total (= E + n)
}

__global__ __launch_bounds__(1024) void k_scanc(const int* __restrict__ cnt,
                                                const int* __restrict__ bsum,
                                                int* __restrict__ off, int n) {
  __shared__ int wsum[16];
  int i = blockIdx.x * 1024 + threadIdx.x;
  int v = (i < n) ? cnt[i] + 1 : 0;   // +1: self-loop
  int orig = v;
  int lane = threadIdx.x & 63, wid = threadIdx.x >> 6;
#pragma unroll
  for (int d = 1; d < 64; d <<= 1) {
    int u = __shfl_up(v, d, 64);
    if (lane >= d) v += u;
  }
  if (lane == 63) wsum[wid] = v;
  __syncthreads();
  if (wid == 0) {
    int s = (lane < 16) ? wsum[lane] : 0;
#pragma unroll
    for (int d = 1; d < 16; d <<= 1) {
      int u = __shfl_up(s, d, 64);
      if (lane >= d) s += u;
    }
    if (lane < 16) wsum[lane] = s;
  }
  __syncthreads();
  if (wid > 0) v += wsum[wid - 1];
  if (i < n) off[i] = bsum[blockIdx.x] + v - orig;  // exclusive
}

// MERGED: gemm1 blocks [0, g1) + scatter blocks [g1, ...).
// gemm1 depends only on wTg; scatter only on offs/rank — independent of each other.
__global__ __launch_bounds__(256) void k_gs(const float* __restrict__ x,
                                            const unsigned short* __restrict__ wTg,
                                            const float* __restrict__ a_src,
                                            const float* __restrict__ a_dst,
                                            unsigned short* __restrict__ h1,
                                            float* __restrict__ as1,
                                            float* __restrict__ ad1, int n,
                                            const int* __restrict__ ei,
                                            const int* __restrict__ off,
                                            const int* __restrict__ rank,
                                            int* __restrict__ adj, int E, int g1) {
  __shared__ __align__(16) unsigned short xs[64][136];   // 17.4 KB
  __shared__ __align__(16) unsigned short wt[128][136];  // 34.8 KB
  if ((int)blockIdx.x >= g1) {
    // ---- scatter: atomic-free, 4 edges per thread; self-loops in tail range ----
    int idx = (blockIdx.x - g1) * 256 + threadIdx.x;
    int nq = (E + 3) >> 2;
    if (idx < nq) {
      int e0 = idx * 4;
      if (e0 + 3 < E) {
        int4 s = *(const int4*)&ei[e0];
        int4 d = *(const int4*)&ei[E + e0];
        int4 r = *(const int4*)&rank[e0];
        adj[off[d.x] + 1 + r.x] = s.x;
        adj[off[d.y] + 1 + r.y] = s.y;
        adj[off[d.z] + 1 + r.z] = s.z;
        adj[off[d.w] + 1 + r.w] = s.w;
      } else {
        for (int e = e0; e < E; ++e) adj[off[ei[E + e]] + 1 + rank[e]] = ei[e];
      }
    } else if (idx < nq + n) {
      int i = idx - nq;
      adj[off[i]] = i;  // self loop
    }
    return;
  }
  // ---- gemm1 via MFMA bf16 (R9-proven): h1(bf16) = x @ W1, fused alphas ----
  int t = threadIdx.x;
  int lane = t & 63, w = t >> 6;
  int l15 = lane & 15;
  {
    const uint4* src = (const uint4*)wTg;
    uint4* dst = (uint4*)&wt[0][0];
    for (int i = t; i < 2176; i += 256) dst[i] = src[i];
  }
  float as_c[8], ad_c[8];
#pragma unroll
  for (int ct = 0; ct < 8; ++ct) {
    as_c[ct] = a_src[ct * 16 + l15];
    ad_c[ct] = a_dst[ct * 16 + l15];
  }
  int tr = t >> 5, tc = t & 31;
  int arow = w * 16 + l15;          // A-frag row within tile
  int koff = (lane >> 4) * 8;       // K offset within 32-wide block
  int row0 = blockIdx.x << 6;
#pragma unroll
  for (int rr = 0; rr < 64; rr += 8) {
    int r = rr + tr, gr = row0 + r;
    float4 v = make_float4(0.f, 0.f, 0.f, 0.f);
    if (gr < n) v = *(const float4*)&x[(size_t)gr * 128 + tc * 4];
    ushort4 b;
    b.x = f2bf(v.x); b.y = f2bf(v.y); b.z = f2bf(v.z); b.w = f2bf(v.w);
    *(ushort4*)&xs[r][tc * 4] = b;
  }
  __syncthreads();
  f32x4 acc[8];
#pragma unroll
  for (int ct = 0; ct < 8; ++ct) acc[ct] = f32x4{0.f, 0.f, 0.f, 0.f};
#pragma unroll
  for (int kb = 0; kb < 4; ++kb) {
    bf16x8 a = *(bf16x8*)&xs[arow][kb * 32 + koff];
#pragma unroll
    for (int ct = 0; ct < 8; ++ct) {
      bf16x8 b = *(bf16x8*)&wt[ct * 16 + l15][kb * 32 + koff];
      acc[ct] = __builtin_amdgcn_mfma_f32_16x16x32_bf16(a, b, acc[ct], 0, 0, 0);
    }
  }
  // epilogue: h1 (bf16) + per-head alpha projections
  int orow = (lane >> 4) * 4;
#pragma unroll
  for (int r = 0; r < 4; ++r) {
    int gr = row0 + w * 16 + orow + r;
    bool ok = gr < n;
#pragma unroll
    for (int ct = 0; ct < 8; ++ct)
      if (ok) h1[(size_t)gr * 128 + ct * 16 + l15] = f2bf(acc[ct][r]);
#pragma unroll
    for (int h = 0; h < 4; ++h) {
      float ps = acc[2 * h][r] * as_c[2 * h] + acc[2 * h + 1][r] * as_c[2 * h + 1];
      float pd = acc[2 * h][r] * ad_c[2 * h] + acc[2 * h + 1][r] * ad_c[2 * h + 1];
      ps += __shfl_xor(ps, 1); ps += __shfl_xor(ps, 2);
      ps += __shfl_xor(ps, 4); ps += __shfl_xor(ps, 8);
      pd += __shfl_xor(pd, 1); pd += __shfl_xor(pd, 2);
      pd += __shfl_xor(pd, 4); pd += __shfl_xor(pd, 8);
      if (ok && l15 == 0) {
        as1[gr * 4 + h] = ps;
        ad1[gr * 4 + h] = pd;
      }
    }
  }
}

// ---------------- conv1 + FUSED gemm2: single-pass aggregation, then the
// 16-lane group (holding the node's full 128-ch x2 row, 8 ch/lane) computes
// h2 = x2 @ W2 in-register (scalar W2 reads — R16 lesson). x2 never
// materializes. as2 PACKED into h2 row slot 10 (one 64B line in conv2).

__global__ __launch_bounds__(256) void k_conv1(const int* __restrict__ off,
                                               const int* __restrict__ adj,
                                               const unsigned short* __restrict__ h1,
                                               const float* __restrict__ as1,
                                               const float* __restrict__ ad1,
                                               const float* __restrict__ b1,
                                               const float* __restrict__ W2,
                                               const float* __restrict__ a_src2,
                                               const float* __restrict__ a_dst2,
                                               float* __restrict__ h2,
                                               float* __restrict__ ad2, int n) {
  int wid = (blockIdx.x * 256 + threadIdx.x) >> 6;  // global wave id
  int lane = threadIdx.x & 63;
  int grp = lane >> 4;       // node slot within wave
  int l16 = lane & 15;
  int node = wid * 4 + grp;
  bool active = node < n;
  int beg = 0, end = 0;
  float4 adv = make_float4(0.f, 0.f, 0.f, 0.f);
  if (active) {
    beg = off[node];
    end = off[node + 1];
    adv = *(const float4*)&ad1[node * 4];
  }
  int hh = (l16 >> 2) & 3;   // head for this lane's channels AND its weight slot
  int esub = l16 & 3;        // edge slot within chunk quarter
  float adh = hh == 0 ? adv.x : hh == 1 ? adv.y : hh == 2 ? adv.z : adv.w;
  int c0 = l16 * 8;          // 8 bf16 channels per lane
  float acc[8] = {};
  float zacc = 0.f;
  for (int e0 = beg; e0 < end; e0 += 16) {
    int sa = 0, sb = 0, sc = 0, sd = 0;
    float wa = 0.f, wb = 0.f, wc = 0.f, wdd = 0.f;
    int ea = e0 + esub, eb = e0 + 4 + esub, ec = e0 + 8 + esub, ed = e0 + 12 + esub;
    if (ea < end) {
      sa = adj[ea];
      float v = as1[sa * 4 + hh] + adh;
      v = v > 0.f ? v : 0.2f * v;
      wa = __expf(v);
    }
    if (eb < end) {
      sb = adj[eb];
      float v = as1[sb * 4 + hh] + adh;
      v = v > 0.f ? v : 0.2f * v;
      wb = __expf(v);
    }
    if (ec < end) {
      sc = adj[ec];
      float v = as1[sc * 4 + hh] + adh;
      v = v > 0.f ? v : 0.2f * v;
      wc = __expf(v);
    }
    if (ed < end) {
      sd = adj[ed];
      float v = as1[sd * 4 + hh] + adh;
      v = v > 0.f ? v : 0.2f * v;
      wdd = __expf(v);
    }
    zacc += wa + wb + wc + wdd;
    // consume 16 edges; src/weight broadcast from lane (lane&60)|(j&3)
#pragma unroll
    for (int j = 0; j < 16; ++j) {
      int sl = (lane & 60) | (j & 3);
      int s = (j < 4) ? __shfl(sa, sl) : (j < 8) ? __shfl(sb, sl)
             : (j < 12) ? __shfl(sc, sl) : __shfl(sd, sl);
      float w = (j < 4) ? __shfl(wa, sl) : (j < 8) ? __shfl(wb, sl)
             : (j < 12) ? __shfl(wc, sl) : __shfl(wdd, sl);
      if (e0 + j < end) {  // uniform within the 16-lane group
        uint4 q = *(const uint4*)&h1[(size_t)s * 128 + c0];
        acc[0] += w * __uint_as_float(q.x << 16);
        acc[1] += w * __uint_as_float(q.x & 0xffff0000u);
        acc[2] += w * __uint_as_float(q.y << 16);
        acc[3] += w * __uint_as_float(q.y & 0xffff0000u);
        acc[4] += w * __uint_as_float(q.z << 16);
        acc[5] += w * __uint_as_float(q.z & 0xffff0000u);
        acc[6] += w * __uint_as_float(q.w << 16);
        acc[7] += w * __uint_as_float(q.w & 0xffff0000u);
      }
    }
  }
  // z for head hh: reduce over the 4 esub lanes (lane bits 0,1)
  zacc += __shfl_xor(zacc, 1);
  zacc += __shfl_xor(zacc, 2);
  // bias + ELU -> o[8] = this lane's 8 channels of x2[node]
  float inv = 1.0f / (zacc + 1e-16f);
  float o[8];
#pragma unroll
  for (int j = 0; j < 8; ++j) {
    float v = acc[j] * inv + b1[c0 + j];
    o[j] = v > 0.f ? v : __expf(v) - 1.f;  // ELU fused
  }
  // ---- fused gemm2: acc2[c] = sum_k x2[node][k] * W2[k][c] ----
  const float* wr = &W2[c0 * 10];
  float acc2[10];
#pragma unroll
  for (int c = 0; c < 10; ++c) {
    acc2[c] = o[0] * wr[c]      + o[1] * wr[10 + c] + o[2] * wr[20 + c] +
              o[3] * wr[30 + c] + o[4] * wr[40 + c] + o[5] * wr[50 + c] +
              o[6] * wr[60 + c] + o[7] * wr[70 + c];
  }
#pragma unroll
  for (int c = 0; c < 10; ++c) {
#pragma unroll
    for (int d = 1; d < 16; d <<= 1) acc2[c] += __shfl_xor(acc2[c], d);
  }
  if (active && l16 == 0) {
    float s = 0.f, ds = 0.f;
#pragma unroll
    for (int c = 0; c < 10; ++c) {
      h2[(size_t)node * 16 + c] = acc2[c];   // padded stride 16
      s += acc2[c] * a_src2[c];
      ds += acc2[c] * a_dst2[c];
    }
    h2[(size_t)node * 16 + 10] = s;          // as2 packed into the same 64B line
    ad2[node] = ds;
  }
}

// ---------------- conv2: SINGLE-PASS; ONE 64B line per edge (h2 row + packed as2) ----

__global__ __launch_bounds__(256) void k_conv2(const int* __restrict__ off,
                                               const int* __restrict__ adj,
                                               const float* __restrict__ h2,
                                               const float* __restrict__ ad2,
                                               const float* __restrict__ b2,
                                               float* __restrict__ out, int n) {
  int wid = (blockIdx.x * 256 + threadIdx.x) >> 6;
  int lane = threadIdx.x & 63;
  int grp = lane >> 4;
  int l16 = lane & 15;
  int node = wid * 4 + grp;
  bool active = node < n;
  int beg = 0, end = 0;
  float adv = 0.f;
  if (active) {
    beg = off[node];
    end = off[node + 1];
    adv = ad2[node];
  }
  float z = 0.f;
  float acc[10] = {};
  for (int e = beg + l16; e < end; e += 16) {
    int s = adj[e];
    const float4* hp = (const float4*)&h2[(size_t)s * 16];
    float4 hA = hp[0], hB = hp[1], hC = hp[2];   // hC = {h8, h9, as2, pad}
    float v = hC.z + adv;
    v = v > 0.f ? v : 0.2f * v;
    float wgt = __expf(v);
    z += wgt;
    acc[0] += wgt * hA.x; acc[1] += wgt * hA.y;
    acc[2] += wgt * hA.z; acc[3] += wgt * hA.w;
    acc[4] += wgt * hB.x; acc[5] += wgt * hB.y;
    acc[6] += wgt * hB.z; acc[7] += wgt * hB.w;
    acc[8] += wgt * hC.x; acc[9] += wgt * hC.y;
  }
#pragma unroll
  for (int c = 0; c < 10; ++c) {
#pragma unroll
    for (int d = 1; d < 16; d <<= 1) acc[c] += __shfl_xor(acc[c], d);
  }
#pragma unroll
  for (int d = 1; d < 16; d <<= 1) z += __shfl_xor(z, d);
  if (active && l16 == 0) {
    float inv = 1.0f / (z + 1e-16f);
#pragma unroll
    for (int c = 0; c < 10; ++c) out[(size_t)node * 10 + c] = acc[c] * inv + b2[c];
  }
}

// ---------------- launch ----------------

extern "C" void kernel_launch(void* const* d_in, const int* in_sizes, int n_in,
                              void* d_out, int out_size, void* d_ws, size_t ws_size,
                              hipStream_t stream) {
  const float* x      = (const float*)d_in[0];
  const int* ei       = (const int*)d_in[1];
  const float* W1     = (const float*)d_in[2];
  const float* a_src1 = (const float*)d_in[3];
  const float* a_dst1 = (const float*)d_in[4];
  const float* b1     = (const float*)d_in[5];
  const float* W2     = (const float*)d_in[6];
  const float* a_src2 = (const float*)d_in[7];
  const float* a_dst2 = (const float*)d_in[8];
  const float* b2     = (const float*)d_in[9];
  float* out = (float*)d_out;
  const int N = in_sizes[0] / 128;
  const int E = in_sizes[1] / 2;

  char* ws = (char*)d_ws;
  size_t o = 0;
  auto alloc = [&](size_t bytes) -> void* {
    void* p = ws + o;
    o += (bytes + 255) & ~(size_t)255;
    return p;
  };
  int* cnt    = (int*)alloc((size_t)N * 4);
  int* rank_  = (int*)alloc((size_t)E * 4);
  int* offs   = (int*)alloc((size_t)(N + 1) * 4);
  int* bsum   = (int*)alloc(1024 * 4);
  int* adj    = (int*)alloc((size_t)(E + N) * 4);
  unsigned short* h1  = (unsigned short*)alloc((size_t)N * 128 * 2);  // bf16
  unsigned short* wTg = (unsigned short*)alloc(128 * 136 * 2);        // bf16 W1^T padded
  float* a_s1 = (float*)alloc((size_t)N * 4 * 4);
  float* a_d1 = (float*)alloc((size_t)N * 4 * 4);
  float* h2   = (float*)alloc((size_t)N * 16 * 4);   // padded stride 16; slot10 = as2
  float* a_d2 = (float*)alloc((size_t)N * 4);

  int nb = (N + 1023) / 1024;
  int g1 = (N + 63) / 64;                    // gemm1 tiles
  int nq = (E + 3) / 4;
  int nwb = (128 * 136 + 255) / 256;         // wprep blocks
  int ncb = (nq + 255) / 256;                // count blocks
  int nsb = (nq + N + 255) / 256;            // scatter blocks
  hipMemsetAsync(cnt, 0, (size_t)N * 4, stream);
  k_prep<<<nwb + ncb, 256, 0, stream>>>(W1, wTg, ei, cnt, rank_, E, nwb);
  k_bsum<<<nb, 1024, 0, stream>>>(cnt, bsum, N);
  k_scanb<<<1, 64, 0, stream>>>(bsum, offs, nb, N);
  k_scanc<<<nb, 1024, 0, stream>>>(cnt, bsum, offs, N);
  k_gs<<<g1 + nsb, 256, 0, stream>>>(x, wTg, a_src1, a_dst1, h1, a_s1, a_d1, N,
                                     ei, offs, rank_, adj, E, g1);
  k_conv1<<<(N + 15) / 16, 256, 0, stream>>>(offs, adj, h1, a_s1, a_d1, b1,
                                             W2, a_src2, a_dst2, h2, a_d2, N);
  k_conv2<<<(N + 15) / 16, 256, 0, stream>>>(offs, adj, h2, a_d2, b2, out, N);
}